// Round 9
// baseline (123.026 us; speedup 1.0000x reference)
//
#include <hip/hip_runtime.h>

#define NROW 200000
#define RDIM 32
#define BATCH 131072
#define STEP 0.01f
#define CAP 8                       // bucket capacity; Poisson(0.655) tail > 8 ~ 3e-8/row
#define ROWS3 (3 * NROW)            // 600000
#define APPLY_BLOCKS 2048
#define APPLY_THREADS 256
#define NSUB ((APPLY_BLOCKS * APPLY_THREADS) / 8)   // 65536 subgroups
#define NITER ((ROWS3 + NSUB - 1) / NSUB)           // 10

// ===========================================================================
// FAST PATH ws layout (~43.4 MB), all 8B-aligned:
//   cnt    int[3*NROW]      \ one contiguous memset(0)
//   head   int[3*NROW]      /  (head uses idx+1 encoding; 0 = empty)
//   nxt    int[3*BATCH]
//   bucket int[3*NROW*CAP]
//   scal   float2[BATCH]    (A = ki - phi*wi, wi)
//   Lp     float[BATCH*32]  (L_r * g0*g1*g2)
// ===========================================================================

// Merged precompute + bucket build. 8 lanes per batch element, float4 I/O.
__global__ __launch_bounds__(256) void em_pre_bkt(
    const float* __restrict__ U0, const float* __restrict__ U1,
    const float* __restrict__ U2, const float* __restrict__ L,
    const float* __restrict__ bv, const int* __restrict__ be,
    int* __restrict__ cnt, int* __restrict__ head, int* __restrict__ nxt,
    int* __restrict__ bucket, float2* __restrict__ scal, float* __restrict__ LpBuf)
{
    int tid = blockIdx.x * blockDim.x + threadIdx.x;
    int i   = tid >> 3;          // batch element
    int sub = tid & 7;           // 4-float slot
    if (i >= BATCH) return;

    int e0 = be[i * 3 + 0];
    int e1 = be[i * 3 + 1];
    int e2 = be[i * 3 + 2];

    float4 g0 = *(const float4*)(U0 + (size_t)e0 * RDIM + sub * 4);
    float4 g1 = *(const float4*)(U1 + (size_t)e1 * RDIM + sub * 4);
    float4 g2 = *(const float4*)(U2 + (size_t)e2 * RDIM + sub * 4);
    float4 Lv = *(const float4*)(L + sub * 4);

    float4 Lp;
    Lp.x = Lv.x * g0.x * g1.x * g2.x;
    Lp.y = Lv.y * g0.y * g1.y * g2.y;
    Lp.z = Lv.z * g0.z * g1.z * g2.z;
    Lp.w = Lv.w * g0.w * g1.w * g2.w;

    float phi = (Lp.x + Lp.y) + (Lp.z + Lp.w);
    phi += __shfl_xor(phi, 1);
    phi += __shfl_xor(phi, 2);
    phi += __shfl_xor(phi, 4);

    float wi = 0.5f / phi * tanhf(0.5f * phi);

    *(float4*)(LpBuf + (size_t)i * RDIM + sub * 4) = Lp;

    if (sub == 0) {
        float A = (bv[i] - 0.5f) - phi * wi;
        scal[i] = make_float2(A, wi);
    }
    if (sub < 3) {
        int row = (sub == 0) ? e0 : (sub == 1) ? e1 : e2;
        int rid = sub * NROW + row;
        int slot = atomicAdd(&cnt[rid], 1);
        if (slot < CAP) {
            bucket[(size_t)rid * CAP + slot] = i;
        } else {
            int idx = i * 3 + sub;                       // idx+1 encoding
            nxt[idx] = atomicExch(&head[rid], idx + 1);
        }
    }
}

// ---------------------------------------------------------------------------
// Pipelined apply: grid-strided rows, 3-stage software pipeline.
// ---------------------------------------------------------------------------
struct L1S {
    int    n;
    int4   bk;
    float4 sin, tin, gd;
};
struct L2S {
    float2 aw0, aw1, aw2, aw3;
    float4 p0, p1, p2, p3;
};

__device__ __forceinline__ void load_l1(
    L1S& s, int rid, int sub,
    const float* __restrict__ U0, const float* __restrict__ U1,
    const float* __restrict__ U2,
    const float* __restrict__ S0, const float* __restrict__ S1,
    const float* __restrict__ S2,
    const float* __restrict__ T0, const float* __restrict__ T1,
    const float* __restrict__ T2,
    const int* __restrict__ cnt, const int* __restrict__ bucket)
{
    int rc  = (rid < ROWS3) ? rid : (ROWS3 - 1);
    int d   = rc / NROW;
    int row = rc - d * NROW;
    const float* Ss = (d == 0) ? S0 : (d == 1) ? S1 : S2;
    const float* Ts = (d == 0) ? T0 : (d == 1) ? T1 : T2;
    const float* Us = (d == 0) ? U0 : (d == 1) ? U1 : U2;
    size_t off = (size_t)row * RDIM + sub * 4;
    s.n   = cnt[rc];
    s.bk  = *(const int4*)(bucket + (size_t)rc * CAP);
    s.sin = *(const float4*)(Ss + off);
    s.tin = *(const float4*)(Ts + off);
    s.gd  = *(const float4*)(Us + off);
}

__device__ __forceinline__ void load_l2(
    L2S& l, const L1S& s, int sub,
    const float2* __restrict__ scal, const float* __restrict__ LpBuf)
{
    int n  = s.n;
    int i0 = (n > 0) ? s.bk.x : 0;
    int i1 = (n > 1) ? s.bk.y : 0;
    int i2 = (n > 2) ? s.bk.z : 0;
    int i3 = (n > 3) ? s.bk.w : 0;
    l.aw0 = scal[i0];
    l.aw1 = scal[i1];
    l.aw2 = scal[i2];
    l.aw3 = scal[i3];
    l.p0 = *(const float4*)(LpBuf + (size_t)i0 * RDIM + sub * 4);
    l.p1 = *(const float4*)(LpBuf + (size_t)i1 * RDIM + sub * 4);
    l.p2 = *(const float4*)(LpBuf + (size_t)i2 * RDIM + sub * 4);
    l.p3 = *(const float4*)(LpBuf + (size_t)i3 * RDIM + sub * 4);
    // mask unused slots (slot0 handled by the final touched-select)
    if (n <= 1) { l.aw1.x = 0.f; l.aw1.y = 0.f; }
    if (n <= 2) { l.aw2.x = 0.f; l.aw2.y = 0.f; }
    if (n <= 3) { l.aw3.x = 0.f; l.aw3.y = 0.f; }
}

#define ACC(SA, TA, RG, AW, P)                                          \
{                                                                       \
    float cx = (P).x * (RG).x, cy = (P).y * (RG).y,                     \
          cz = (P).z * (RG).z, cw = (P).w * (RG).w;                     \
    (SA).x += (AW).y * cx * cx;  (SA).y += (AW).y * cy * cy;            \
    (SA).z += (AW).y * cz * cz;  (SA).w += (AW).y * cw * cw;            \
    (TA).x += ((AW).x + (AW).y * (P).x) * cx;                           \
    (TA).y += ((AW).x + (AW).y * (P).y) * cy;                           \
    (TA).z += ((AW).x + (AW).y * (P).z) * cz;                           \
    (TA).w += ((AW).x + (AW).y * (P).w) * cw;                           \
}

__device__ __forceinline__ void compute_store(
    const L1S& s, const L2S& l, int rid, int sub,
    const int* __restrict__ head, const int* __restrict__ nxt,
    const int* __restrict__ bucket,
    const float2* __restrict__ scal, const float* __restrict__ LpBuf,
    float* __restrict__ out)
{
    float4 rg;
    rg.x = __builtin_amdgcn_rcpf(s.gd.x);   // U in [0.05,1] — safe
    rg.y = __builtin_amdgcn_rcpf(s.gd.y);
    rg.z = __builtin_amdgcn_rcpf(s.gd.z);
    rg.w = __builtin_amdgcn_rcpf(s.gd.w);

    float4 sa = make_float4(0.f, 0.f, 0.f, 0.f);
    float4 ta = make_float4(0.f, 0.f, 0.f, 0.f);

    ACC(sa, ta, rg, l.aw0, l.p0)
    ACC(sa, ta, rg, l.aw1, l.p1)
    ACC(sa, ta, rg, l.aw2, l.p2)
    ACC(sa, ta, rg, l.aw3, l.p3)

    int n = s.n;
    if (n > 4) {   // cold: ~5e-4 of rows
        int rc = (rid < ROWS3) ? rid : (ROWS3 - 1);
        int m  = (n < CAP) ? n : CAP;
        for (int j = 4; j < m; ++j) {
            int e = bucket[(size_t)rc * CAP + j];
            float2 aw = scal[e];
            float4 P  = *(const float4*)(LpBuf + (size_t)e * RDIM + sub * 4);
            ACC(sa, ta, rg, aw, P)
        }
        if (n > CAP) {   // essentially never; correctness only
            int t = head[rc];
            while (t != 0) {
                int idx = t - 1;
                int e = idx / 3;
                float2 aw = scal[e];
                float4 P  = *(const float4*)(LpBuf + (size_t)e * RDIM + sub * 4);
                ACC(sa, ta, rg, aw, P)
                t = nxt[idx];
            }
        }
    }

    bool touched = (n > 0);
    float4 oS, oT;
    oS.x = touched ? (1.0f - STEP) * s.sin.x + STEP * sa.x : s.sin.x;
    oS.y = touched ? (1.0f - STEP) * s.sin.y + STEP * sa.y : s.sin.y;
    oS.z = touched ? (1.0f - STEP) * s.sin.z + STEP * sa.z : s.sin.z;
    oS.w = touched ? (1.0f - STEP) * s.sin.w + STEP * sa.w : s.sin.w;
    oT.x = touched ? (1.0f - STEP) * s.tin.x + STEP * ta.x : s.tin.x;
    oT.y = touched ? (1.0f - STEP) * s.tin.y + STEP * ta.y : s.tin.y;
    oT.z = touched ? (1.0f - STEP) * s.tin.z + STEP * ta.z : s.tin.z;
    oT.w = touched ? (1.0f - STEP) * s.tin.w + STEP * ta.w : s.tin.w;

    if (rid < ROWS3) {
        size_t off = (size_t)rid * RDIM + sub * 4;
        *(float4*)(out + off) = oS;
        *(float4*)(out + (size_t)ROWS3 * RDIM + off) = oT;
    }
}

__global__ __launch_bounds__(256) void em_apply_pipe(
    const float* __restrict__ U0, const float* __restrict__ U1,
    const float* __restrict__ U2,
    const float* __restrict__ S0, const float* __restrict__ S1,
    const float* __restrict__ S2,
    const float* __restrict__ T0, const float* __restrict__ T1,
    const float* __restrict__ T2,
    const int* __restrict__ cnt, const int* __restrict__ head,
    const int* __restrict__ nxt, const int* __restrict__ bucket,
    const float2* __restrict__ scal, const float* __restrict__ LpBuf,
    float* __restrict__ out)
{
    int tid  = blockIdx.x * blockDim.x + threadIdx.x;
    int gsub = tid >> 3;             // subgroup id in [0, NSUB)
    int sub  = tid & 7;

    L1S s[3];
    L2S l[2];

    // prologue: 2 L1 stages in flight, first L2 issued
    load_l1(s[0], gsub,          sub, U0,U1,U2, S0,S1,S2, T0,T1,T2, cnt, bucket);
    load_l1(s[1], gsub + NSUB,   sub, U0,U1,U2, S0,S1,S2, T0,T1,T2, cnt, bucket);
    load_l2(l[0], s[0], sub, scal, LpBuf);

    #pragma unroll
    for (int i = 0; i < NITER; ++i) {
        if (i + 2 < NITER)
            load_l1(s[(i + 2) % 3], gsub + (i + 2) * NSUB, sub,
                    U0,U1,U2, S0,S1,S2, T0,T1,T2, cnt, bucket);
        if (i + 1 < NITER)
            load_l2(l[(i + 1) & 1], s[(i + 1) % 3], sub, scal, LpBuf);
        compute_store(s[i % 3], l[i & 1], gsub + i * NSUB, sub,
                      head, nxt, bucket, scal, LpBuf, out);
    }
}

// ===========================================================================
// FALLBACK (chain version) — used only if ws too small for buckets
// ===========================================================================
__global__ __launch_bounds__(256) void em_pre(
    const float* __restrict__ U0, const float* __restrict__ U1,
    const float* __restrict__ U2, const float* __restrict__ L,
    const float* __restrict__ bv, const int* __restrict__ be,
    int* __restrict__ head, int* __restrict__ nxt,
    float2* __restrict__ scal, float* __restrict__ LpBuf)
{
    int tid = blockIdx.x * blockDim.x + threadIdx.x;
    int i   = tid >> 3;
    int sub = tid & 7;
    if (i >= BATCH) return;

    int e0 = be[i * 3 + 0];
    int e1 = be[i * 3 + 1];
    int e2 = be[i * 3 + 2];

    float4 g0 = *(const float4*)(U0 + (size_t)e0 * RDIM + sub * 4);
    float4 g1 = *(const float4*)(U1 + (size_t)e1 * RDIM + sub * 4);
    float4 g2 = *(const float4*)(U2 + (size_t)e2 * RDIM + sub * 4);
    float4 Lv = *(const float4*)(L + sub * 4);

    float4 Lp;
    Lp.x = Lv.x * g0.x * g1.x * g2.x;
    Lp.y = Lv.y * g0.y * g1.y * g2.y;
    Lp.z = Lv.z * g0.z * g1.z * g2.z;
    Lp.w = Lv.w * g0.w * g1.w * g2.w;

    float phi = (Lp.x + Lp.y) + (Lp.z + Lp.w);
    phi += __shfl_xor(phi, 1);
    phi += __shfl_xor(phi, 2);
    phi += __shfl_xor(phi, 4);

    float wi = 0.5f / phi * tanhf(0.5f * phi);

    *(float4*)(LpBuf + (size_t)i * RDIM + sub * 4) = Lp;

    if (sub == 0) {
        float A = (bv[i] - 0.5f) - phi * wi;
        scal[i] = make_float2(A, wi);
    }
    if (sub < 3) {
        int row = (sub == 0) ? e0 : (sub == 1) ? e1 : e2;
        int idx = i * 3 + sub;
        nxt[idx] = atomicExch(&head[sub * NROW + row], idx + 1);
    }
}

__global__ __launch_bounds__(256) void em_apply_vec(
    const float* __restrict__ U0, const float* __restrict__ U1,
    const float* __restrict__ U2,
    const float* __restrict__ S0, const float* __restrict__ S1,
    const float* __restrict__ S2,
    const float* __restrict__ T0, const float* __restrict__ T1,
    const float* __restrict__ T2,
    const int* __restrict__ head, const int* __restrict__ nxt,
    const float2* __restrict__ scal, const float* __restrict__ LpBuf,
    float* __restrict__ out)
{
    int tid = blockIdx.x * blockDim.x + threadIdx.x;
    int rid = tid >> 3;
    int sub = tid & 7;
    if (rid >= ROWS3) return;

    int d   = rid / NROW;
    int row = rid - d * NROW;

    const float* Ud   = (d == 0) ? U0 : (d == 1) ? U1 : U2;
    const float* Ssrc = (d == 0) ? S0 : (d == 1) ? S1 : S2;
    const float* Tsrc = (d == 0) ? T0 : (d == 1) ? T1 : T2;

    size_t roff = (size_t)row * RDIM + sub * 4;
    float4 s_in = *(const float4*)(Ssrc + roff);
    float4 t_in = *(const float4*)(Tsrc + roff);

    int    t  = head[rid];
    float4 oS = s_in;
    float4 oT = t_in;

    if (t != 0) {
        float4 gd = *(const float4*)(Ud + roff);
        float4 rg;
        rg.x = __builtin_amdgcn_rcpf(gd.x);
        rg.y = __builtin_amdgcn_rcpf(gd.y);
        rg.z = __builtin_amdgcn_rcpf(gd.z);
        rg.w = __builtin_amdgcn_rcpf(gd.w);

        float4 sa = make_float4(0.f, 0.f, 0.f, 0.f);
        float4 ta = make_float4(0.f, 0.f, 0.f, 0.f);
        while (t != 0) {
            int idx = t - 1;
            int e = idx / 3;
            float2 aw = scal[e];
            float4 Lp = *(const float4*)(LpBuf + (size_t)e * RDIM + sub * 4);
            ACC(sa, ta, rg, aw, Lp)
            t = nxt[idx];
        }
        oS.x = (1.0f - STEP) * s_in.x + STEP * sa.x;
        oS.y = (1.0f - STEP) * s_in.y + STEP * sa.y;
        oS.z = (1.0f - STEP) * s_in.z + STEP * sa.z;
        oS.w = (1.0f - STEP) * s_in.w + STEP * sa.w;
        oT.x = (1.0f - STEP) * t_in.x + STEP * ta.x;
        oT.y = (1.0f - STEP) * t_in.y + STEP * ta.y;
        oT.z = (1.0f - STEP) * t_in.z + STEP * ta.z;
        oT.w = (1.0f - STEP) * t_in.w + STEP * ta.w;
    }

    size_t offS = (size_t)rid * RDIM + sub * 4;
    *(float4*)(out + offS) = oS;
    *(float4*)(out + (size_t)ROWS3 * RDIM + offS) = oT;
}

// ===========================================================================
extern "C" void kernel_launch(void* const* d_in, const int* in_sizes, int n_in,
                              void* d_out, int out_size, void* d_ws, size_t ws_size,
                              hipStream_t stream)
{
    // setup_inputs() insertion order: U0,S0,T0, U1,S1,T1, U2,S2,T2, L, bv, be
    const float* U0 = (const float*)d_in[0];
    const float* S0 = (const float*)d_in[1];
    const float* T0 = (const float*)d_in[2];
    const float* U1 = (const float*)d_in[3];
    const float* S1 = (const float*)d_in[4];
    const float* T1 = (const float*)d_in[5];
    const float* U2 = (const float*)d_in[6];
    const float* S2 = (const float*)d_in[7];
    const float* T2 = (const float*)d_in[8];
    const float* L  = (const float*)d_in[9];
    const float* bv = (const float*)d_in[10];
    const int*   be = (const int*)d_in[11];

    float* out = (float*)d_out;

    const size_t rows3 = (size_t)ROWS3;
    const size_t nxt_n = (size_t)3 * BATCH;
    const size_t bkt_n = rows3 * CAP;

    const size_t ws_fast = (2 * rows3 + nxt_n + bkt_n) * sizeof(int)
                         + (size_t)BATCH * sizeof(float2)
                         + (size_t)BATCH * RDIM * sizeof(float);   // ~43.4 MB
    const size_t ws_mid  = (rows3 + nxt_n) * sizeof(int)
                         + (size_t)BATCH * sizeof(float2)
                         + (size_t)BATCH * RDIM * sizeof(float);   // ~21.8 MB

    if (ws_size >= ws_fast) {
        // ---- fast path: bucketed CSR + pipelined apply ----
        int*    cnt    = (int*)d_ws;
        int*    head_  = cnt + rows3;
        int*    nxt    = head_ + rows3;
        int*    bucket = nxt + nxt_n;
        float2* scal   = (float2*)(bucket + bkt_n);
        float*  LpBuf  = (float*)(scal + BATCH);

        // cnt=0 and head=0 (idx+1 encoding) in ONE memset
        hipMemsetAsync(cnt, 0, 2 * rows3 * sizeof(int), stream);

        int pblocks = (BATCH * 8 + 255) / 256;    // 4096
        em_pre_bkt<<<pblocks, 256, 0, stream>>>(U0, U1, U2, L, bv, be,
                                                cnt, head_, nxt, bucket,
                                                scal, LpBuf);

        em_apply_pipe<<<APPLY_BLOCKS, APPLY_THREADS, 0, stream>>>(
            U0, U1, U2, S0, S1, S2, T0, T1, T2,
            cnt, head_, nxt, bucket, scal, LpBuf, out);
    } else if (ws_size >= ws_mid) {
        // ---- fallback: linked-list version ----
        int*    head_ = (int*)d_ws;
        int*    nxt   = head_ + rows3;
        float2* scal  = (float2*)(nxt + nxt_n);
        float*  LpBuf = (float*)(scal + BATCH);

        hipMemsetAsync(head_, 0, rows3 * sizeof(int), stream);

        int pblocks = (BATCH * 8 + 255) / 256;
        em_pre<<<pblocks, 256, 0, stream>>>(U0, U1, U2, L, bv, be,
                                            head_, nxt, scal, LpBuf);

        long athreads = (long)ROWS3 * 8;
        int  ablocks  = (int)((athreads + 255) / 256);
        em_apply_vec<<<ablocks, 256, 0, stream>>>(U0, U1, U2, S0, S1, S2,
                                                  T0, T1, T2, head_, nxt,
                                                  scal, LpBuf, out);
    }
}

// Round 10
// 115.700 us; speedup vs baseline: 1.0633x; 1.0633x over previous
//
#include <hip/hip_runtime.h>

#define NROW 200000
#define RDIM 32
#define BATCH 131072
#define STEP 0.01f
#define CAPB 4                      // inline bucket slots; P(n>4) ~ 3.5e-4/row
#define ROWS3 (3 * NROW)            // 600000

// ===========================================================================
// FAST PATH ws layout (~43.4 MB), all 8B-aligned:
//   cnt     int[ROWS3]       \ one contiguous memset(0)
//   head    int[ROWS3]       /  (idx+1 encoding; 0 = empty; overflow only)
//   nxt     int[3*BATCH]
//   bucket2 int2[ROWS3*CAPB] {e, bf16(A)<<16 | bf16(wi)}
//   scal    float2[BATCH]    (A, wi) fp32 — overflow cold path only
//   Lp      float[BATCH*32]  (L_r * g0*g1*g2)
// ===========================================================================

__device__ __forceinline__ unsigned f2bf(float x) {
    unsigned u = __float_as_uint(x);
    return (u + 0x8000u) >> 16;          // round-to-nearest-even-ish
}
__device__ __forceinline__ float bf2f(unsigned h) {
    return __uint_as_float(h << 16);
}

// Merged precompute + bucket build. 8 lanes per batch element, float4 I/O.
__global__ __launch_bounds__(256) void em_pre_v10(
    const float* __restrict__ U0, const float* __restrict__ U1,
    const float* __restrict__ U2, const float* __restrict__ L,
    const float* __restrict__ bv, const int* __restrict__ be,
    int* __restrict__ cnt, int* __restrict__ head, int* __restrict__ nxt,
    int* __restrict__ bucket2, float2* __restrict__ scal, float* __restrict__ LpBuf)
{
    int tid = blockIdx.x * blockDim.x + threadIdx.x;
    int i   = tid >> 3;          // batch element
    int sub = tid & 7;           // 4-float slot
    if (i >= BATCH) return;

    int e0 = be[i * 3 + 0];
    int e1 = be[i * 3 + 1];
    int e2 = be[i * 3 + 2];

    float4 g0 = *(const float4*)(U0 + (size_t)e0 * RDIM + sub * 4);
    float4 g1 = *(const float4*)(U1 + (size_t)e1 * RDIM + sub * 4);
    float4 g2 = *(const float4*)(U2 + (size_t)e2 * RDIM + sub * 4);
    float4 Lv = *(const float4*)(L + sub * 4);

    float4 Lp;
    Lp.x = Lv.x * g0.x * g1.x * g2.x;
    Lp.y = Lv.y * g0.y * g1.y * g2.y;
    Lp.z = Lv.z * g0.z * g1.z * g2.z;
    Lp.w = Lv.w * g0.w * g1.w * g2.w;

    float phi = (Lp.x + Lp.y) + (Lp.z + Lp.w);
    phi += __shfl_xor(phi, 1);
    phi += __shfl_xor(phi, 2);
    phi += __shfl_xor(phi, 4);

    float wi = 0.5f / phi * tanhf(0.5f * phi);
    float A  = (bv[i] - 0.5f) - phi * wi;     // all lanes (broadcast bv load)

    *(float4*)(LpBuf + (size_t)i * RDIM + sub * 4) = Lp;

    if (sub == 0) scal[i] = make_float2(A, wi);   // fp32, overflow path only

    if (sub < 3) {
        int row  = (sub == 0) ? e0 : (sub == 1) ? e1 : e2;
        int rid  = sub * NROW + row;
        int slot = atomicAdd(&cnt[rid], 1);
        if (slot < CAPB) {
            int packed = (int)((f2bf(A) << 16) | f2bf(wi));
            *(int2*)(bucket2 + ((size_t)rid * CAPB + slot) * 2) = make_int2(i, packed);
        } else {
            int idx = i * 3 + sub;                       // idx+1 encoding
            nxt[idx] = atomicExch(&head[rid], idx + 1);
        }
    }
}

// ---------------------------------------------------------------------------
// Apply: 8 lanes/row, burst loads, aw inline in bucket, wave-nmax pruning.
// ---------------------------------------------------------------------------
#define ACCS(SA, TA, RG, Aj, Wj, P)                                     \
{                                                                       \
    float cx = (P).x * (RG).x, cy = (P).y * (RG).y,                     \
          cz = (P).z * (RG).z, cw = (P).w * (RG).w;                     \
    (SA).x += (Wj) * cx * cx;  (SA).y += (Wj) * cy * cy;                \
    (SA).z += (Wj) * cz * cz;  (SA).w += (Wj) * cw * cw;                \
    (TA).x += ((Aj) + (Wj) * (P).x) * cx;                               \
    (TA).y += ((Aj) + (Wj) * (P).y) * cy;                               \
    (TA).z += ((Aj) + (Wj) * (P).z) * cz;                               \
    (TA).w += ((Aj) + (Wj) * (P).w) * cw;                               \
}

__global__ __launch_bounds__(256) void em_apply_v10(
    const float* __restrict__ U0, const float* __restrict__ U1,
    const float* __restrict__ U2,
    const float* __restrict__ S0, const float* __restrict__ S1,
    const float* __restrict__ S2,
    const float* __restrict__ T0, const float* __restrict__ T1,
    const float* __restrict__ T2,
    const int* __restrict__ cnt, const int* __restrict__ head,
    const int* __restrict__ nxt, const int* __restrict__ bucket2,
    const float2* __restrict__ scal, const float* __restrict__ LpBuf,
    float* __restrict__ out)
{
    int tid = blockIdx.x * blockDim.x + threadIdx.x;
    int rid = tid >> 3;          // [0, ROWS3); no tail (600000 % 32 == 0)
    int sub = tid & 7;
    if (rid >= ROWS3) return;

    int d   = rid / NROW;        // uniform per block
    int row = rid - d * NROW;

    const float* Ud   = (d == 0) ? U0 : (d == 1) ? U1 : U2;
    const float* Ssrc = (d == 0) ? S0 : (d == 1) ? S1 : S2;
    const float* Tsrc = (d == 0) ? T0 : (d == 1) ? T1 : T2;

    size_t roff = (size_t)row * RDIM + sub * 4;

    // -------- level-1 burst: all independent, coalesced --------
    int    n    = cnt[rid];
    int2   bk   = *(const int2*)(bucket2 + ((size_t)rid * CAPB + (sub & 3)) * 2);
    float4 s_in = *(const float4*)(Ssrc + roff);
    float4 t_in = *(const float4*)(Tsrc + roff);
    float4 gd   = *(const float4*)(Ud + roff);

    // wave-wide max of n (n uniform within each 8-lane subgroup)
    int m = n;
    m = max(m, __shfl_xor(m, 8));
    m = max(m, __shfl_xor(m, 16));
    m = max(m, __shfl_xor(m, 32));

    float4 rg;
    rg.x = __builtin_amdgcn_rcpf(gd.x);   // U in [0.05,1] — safe
    rg.y = __builtin_amdgcn_rcpf(gd.y);
    rg.z = __builtin_amdgcn_rcpf(gd.z);
    rg.w = __builtin_amdgcn_rcpf(gd.w);

    float4 sa = make_float4(0.f, 0.f, 0.f, 0.f);
    float4 ta = make_float4(0.f, 0.f, 0.f, 0.f);

    // wave-uniform pruned slot blocks; per-subgroup masking via zeroed weights
    #define SLOT(J)                                                         \
    {                                                                       \
        int      eJ = __shfl(bk.x, (J), 8);                                 \
        unsigned pJ = (unsigned)__shfl(bk.y, (J), 8);                       \
        float AJ = bf2f(pJ >> 16);                                          \
        float WJ = bf2f(pJ & 0xffffu);                                      \
        if (n <= (J)) { eJ = 0; AJ = 0.f; WJ = 0.f; }                       \
        float4 P = *(const float4*)(LpBuf + (size_t)eJ * RDIM + sub * 4);   \
        ACCS(sa, ta, rg, AJ, WJ, P)                                         \
    }

    if (m > 0) {
        SLOT(0)
        if (m > 1) {
            SLOT(1)
            if (m > 2) {
                SLOT(2)
                if (m > 3) {
                    SLOT(3)
                }
            }
        }
        if (m > CAPB) {           // cold: ~3.5e-4 of rows have n > 4
            if (n > CAPB) {
                int t = head[rid];
                while (t != 0) {
                    int idx = t - 1;
                    int e   = idx / 3;
                    float2 aw = scal[e];
                    float4 P  = *(const float4*)(LpBuf + (size_t)e * RDIM + sub * 4);
                    ACCS(sa, ta, rg, aw.x, aw.y, P)
                    t = nxt[idx];
                }
            }
        }
    }
    #undef SLOT

    bool touched = (n > 0);
    float4 oS, oT;
    oS.x = touched ? (1.0f - STEP) * s_in.x + STEP * sa.x : s_in.x;
    oS.y = touched ? (1.0f - STEP) * s_in.y + STEP * sa.y : s_in.y;
    oS.z = touched ? (1.0f - STEP) * s_in.z + STEP * sa.z : s_in.z;
    oS.w = touched ? (1.0f - STEP) * s_in.w + STEP * sa.w : s_in.w;
    oT.x = touched ? (1.0f - STEP) * t_in.x + STEP * ta.x : t_in.x;
    oT.y = touched ? (1.0f - STEP) * t_in.y + STEP * ta.y : t_in.y;
    oT.z = touched ? (1.0f - STEP) * t_in.z + STEP * ta.z : t_in.z;
    oT.w = touched ? (1.0f - STEP) * t_in.w + STEP * ta.w : t_in.w;

    size_t off = (size_t)rid * RDIM + sub * 4;
    *(float4*)(out + off) = oS;
    *(float4*)(out + (size_t)ROWS3 * RDIM + off) = oT;
}

// ===========================================================================
// FALLBACK (chain version) — used only if ws too small for buckets
// ===========================================================================
__global__ __launch_bounds__(256) void em_pre(
    const float* __restrict__ U0, const float* __restrict__ U1,
    const float* __restrict__ U2, const float* __restrict__ L,
    const float* __restrict__ bv, const int* __restrict__ be,
    int* __restrict__ head, int* __restrict__ nxt,
    float2* __restrict__ scal, float* __restrict__ LpBuf)
{
    int tid = blockIdx.x * blockDim.x + threadIdx.x;
    int i   = tid >> 3;
    int sub = tid & 7;
    if (i >= BATCH) return;

    int e0 = be[i * 3 + 0];
    int e1 = be[i * 3 + 1];
    int e2 = be[i * 3 + 2];

    float4 g0 = *(const float4*)(U0 + (size_t)e0 * RDIM + sub * 4);
    float4 g1 = *(const float4*)(U1 + (size_t)e1 * RDIM + sub * 4);
    float4 g2 = *(const float4*)(U2 + (size_t)e2 * RDIM + sub * 4);
    float4 Lv = *(const float4*)(L + sub * 4);

    float4 Lp;
    Lp.x = Lv.x * g0.x * g1.x * g2.x;
    Lp.y = Lv.y * g0.y * g1.y * g2.y;
    Lp.z = Lv.z * g0.z * g1.z * g2.z;
    Lp.w = Lv.w * g0.w * g1.w * g2.w;

    float phi = (Lp.x + Lp.y) + (Lp.z + Lp.w);
    phi += __shfl_xor(phi, 1);
    phi += __shfl_xor(phi, 2);
    phi += __shfl_xor(phi, 4);

    float wi = 0.5f / phi * tanhf(0.5f * phi);

    *(float4*)(LpBuf + (size_t)i * RDIM + sub * 4) = Lp;

    if (sub == 0) {
        float A = (bv[i] - 0.5f) - phi * wi;
        scal[i] = make_float2(A, wi);
    }
    if (sub < 3) {
        int row = (sub == 0) ? e0 : (sub == 1) ? e1 : e2;
        int idx = i * 3 + sub;
        nxt[idx] = atomicExch(&head[sub * NROW + row], idx + 1);
    }
}

__global__ __launch_bounds__(256) void em_apply_vec(
    const float* __restrict__ U0, const float* __restrict__ U1,
    const float* __restrict__ U2,
    const float* __restrict__ S0, const float* __restrict__ S1,
    const float* __restrict__ S2,
    const float* __restrict__ T0, const float* __restrict__ T1,
    const float* __restrict__ T2,
    const int* __restrict__ head, const int* __restrict__ nxt,
    const float2* __restrict__ scal, const float* __restrict__ LpBuf,
    float* __restrict__ out)
{
    int tid = blockIdx.x * blockDim.x + threadIdx.x;
    int rid = tid >> 3;
    int sub = tid & 7;
    if (rid >= ROWS3) return;

    int d   = rid / NROW;
    int row = rid - d * NROW;

    const float* Ud   = (d == 0) ? U0 : (d == 1) ? U1 : U2;
    const float* Ssrc = (d == 0) ? S0 : (d == 1) ? S1 : S2;
    const float* Tsrc = (d == 0) ? T0 : (d == 1) ? T1 : T2;

    size_t roff = (size_t)row * RDIM + sub * 4;
    float4 s_in = *(const float4*)(Ssrc + roff);
    float4 t_in = *(const float4*)(Tsrc + roff);

    int    t  = head[rid];
    float4 oS = s_in;
    float4 oT = t_in;

    if (t != 0) {
        float4 gd = *(const float4*)(Ud + roff);
        float4 rg;
        rg.x = __builtin_amdgcn_rcpf(gd.x);
        rg.y = __builtin_amdgcn_rcpf(gd.y);
        rg.z = __builtin_amdgcn_rcpf(gd.z);
        rg.w = __builtin_amdgcn_rcpf(gd.w);

        float4 sa = make_float4(0.f, 0.f, 0.f, 0.f);
        float4 ta = make_float4(0.f, 0.f, 0.f, 0.f);
        while (t != 0) {
            int idx = t - 1;
            int e = idx / 3;
            float2 aw = scal[e];
            float4 Lp = *(const float4*)(LpBuf + (size_t)e * RDIM + sub * 4);
            ACCS(sa, ta, rg, aw.x, aw.y, Lp)
            t = nxt[idx];
        }
        oS.x = (1.0f - STEP) * s_in.x + STEP * sa.x;
        oS.y = (1.0f - STEP) * s_in.y + STEP * sa.y;
        oS.z = (1.0f - STEP) * s_in.z + STEP * sa.z;
        oS.w = (1.0f - STEP) * s_in.w + STEP * sa.w;
        oT.x = (1.0f - STEP) * t_in.x + STEP * ta.x;
        oT.y = (1.0f - STEP) * t_in.y + STEP * ta.y;
        oT.z = (1.0f - STEP) * t_in.z + STEP * ta.z;
        oT.w = (1.0f - STEP) * t_in.w + STEP * ta.w;
    }

    size_t offS = (size_t)rid * RDIM + sub * 4;
    *(float4*)(out + offS) = oS;
    *(float4*)(out + (size_t)ROWS3 * RDIM + offS) = oT;
}

// ===========================================================================
extern "C" void kernel_launch(void* const* d_in, const int* in_sizes, int n_in,
                              void* d_out, int out_size, void* d_ws, size_t ws_size,
                              hipStream_t stream)
{
    // setup_inputs() insertion order: U0,S0,T0, U1,S1,T1, U2,S2,T2, L, bv, be
    const float* U0 = (const float*)d_in[0];
    const float* S0 = (const float*)d_in[1];
    const float* T0 = (const float*)d_in[2];
    const float* U1 = (const float*)d_in[3];
    const float* S1 = (const float*)d_in[4];
    const float* T1 = (const float*)d_in[5];
    const float* U2 = (const float*)d_in[6];
    const float* S2 = (const float*)d_in[7];
    const float* T2 = (const float*)d_in[8];
    const float* L  = (const float*)d_in[9];
    const float* bv = (const float*)d_in[10];
    const int*   be = (const int*)d_in[11];

    float* out = (float*)d_out;

    const size_t rows3 = (size_t)ROWS3;
    const size_t nxt_n = (size_t)3 * BATCH;
    const size_t bk2_n = rows3 * CAPB * 2;   // ints

    const size_t ws_fast = (2 * rows3 + nxt_n + bk2_n) * sizeof(int)
                         + (size_t)BATCH * sizeof(float2)
                         + (size_t)BATCH * RDIM * sizeof(float);   // ~43.4 MB
    const size_t ws_mid  = (rows3 + nxt_n) * sizeof(int)
                         + (size_t)BATCH * sizeof(float2)
                         + (size_t)BATCH * RDIM * sizeof(float);   // ~21.8 MB

    if (ws_size >= ws_fast) {
        // ---- fast path: aw-inline buckets + pruned burst apply ----
        int*    cnt     = (int*)d_ws;
        int*    head_   = cnt + rows3;
        int*    nxt     = head_ + rows3;
        int*    bucket2 = nxt + nxt_n;
        float2* scal    = (float2*)(bucket2 + bk2_n);
        float*  LpBuf   = (float*)(scal + BATCH);

        // cnt=0 and head=0 (idx+1 encoding) in ONE memset
        hipMemsetAsync(cnt, 0, 2 * rows3 * sizeof(int), stream);

        int pblocks = (BATCH * 8 + 255) / 256;    // 4096
        em_pre_v10<<<pblocks, 256, 0, stream>>>(U0, U1, U2, L, bv, be,
                                                cnt, head_, nxt, bucket2,
                                                scal, LpBuf);

        long athreads = (long)ROWS3 * 8;          // 4.8M
        int  ablocks  = (int)((athreads + 255) / 256);  // 18750
        em_apply_v10<<<ablocks, 256, 0, stream>>>(U0, U1, U2, S0, S1, S2,
                                                  T0, T1, T2, cnt, head_, nxt,
                                                  bucket2, scal, LpBuf, out);
    } else if (ws_size >= ws_mid) {
        // ---- fallback: linked-list version ----
        int*    head_ = (int*)d_ws;
        int*    nxt   = head_ + rows3;
        float2* scal  = (float2*)(nxt + nxt_n);
        float*  LpBuf = (float*)(scal + BATCH);

        hipMemsetAsync(head_, 0, rows3 * sizeof(int), stream);

        int pblocks = (BATCH * 8 + 255) / 256;
        em_pre<<<pblocks, 256, 0, stream>>>(U0, U1, U2, L, bv, be,
                                            head_, nxt, scal, LpBuf);

        long athreads = (long)ROWS3 * 8;
        int  ablocks  = (int)((athreads + 255) / 256);
        em_apply_vec<<<ablocks, 256, 0, stream>>>(U0, U1, U2, S0, S1, S2,
                                                  T0, T1, T2, head_, nxt,
                                                  scal, LpBuf, out);
    }
}

// Round 11
// 106.988 us; speedup vs baseline: 1.1499x; 1.0814x over previous
//
#include <hip/hip_runtime.h>

#define NROW 200000
#define RDIM 32
#define BATCH 131072
#define STEP 0.01f
#define CAPB 4                      // inline bucket slots; P(n>4) ~ 3.5e-4/row
#define ROWS3 (3 * NROW)            // 600000

// ===========================================================================
// FAST PATH ws layout (~43.4 MB), all 8B-aligned:
//   cnt     int[ROWS3]       \ one contiguous memset(0)
//   head    int[ROWS3]       /  (idx+1 encoding; 0 = empty; overflow only)
//   nxt     int[3*BATCH]
//   bucket2 int[ROWS3*8]     4 slots/row of {e, bf16(A)<<16 | bf16(wi)}
//   scal    float2[BATCH]    (A, wi) fp32 — overflow cold path only
//   Lp      float[BATCH*32]  (L_r * g0*g1*g2)
// ===========================================================================

__device__ __forceinline__ unsigned f2bf(float x) {
    unsigned u = __float_as_uint(x);
    return (u + 0x8000u) >> 16;
}
__device__ __forceinline__ float bf2f(unsigned h) {
    return __uint_as_float(h << 16);
}

// Merged precompute + bucket build. 8 lanes per batch element, float4 I/O.
__global__ __launch_bounds__(256) void em_pre_v11(
    const float* __restrict__ U0, const float* __restrict__ U1,
    const float* __restrict__ U2, const float* __restrict__ L,
    const float* __restrict__ bv, const int* __restrict__ be,
    int* __restrict__ cnt, int* __restrict__ head, int* __restrict__ nxt,
    int* __restrict__ bucket2, float2* __restrict__ scal, float* __restrict__ LpBuf)
{
    int tid = blockIdx.x * blockDim.x + threadIdx.x;
    int i   = tid >> 3;          // batch element
    int sub = tid & 7;           // 4-float slot
    if (i >= BATCH) return;

    int e0 = be[i * 3 + 0];
    int e1 = be[i * 3 + 1];
    int e2 = be[i * 3 + 2];

    float4 g0 = *(const float4*)(U0 + (size_t)e0 * RDIM + sub * 4);
    float4 g1 = *(const float4*)(U1 + (size_t)e1 * RDIM + sub * 4);
    float4 g2 = *(const float4*)(U2 + (size_t)e2 * RDIM + sub * 4);
    float4 Lv = *(const float4*)(L + sub * 4);

    float4 Lp;
    Lp.x = Lv.x * g0.x * g1.x * g2.x;
    Lp.y = Lv.y * g0.y * g1.y * g2.y;
    Lp.z = Lv.z * g0.z * g1.z * g2.z;
    Lp.w = Lv.w * g0.w * g1.w * g2.w;

    float phi = (Lp.x + Lp.y) + (Lp.z + Lp.w);
    phi += __shfl_xor(phi, 1);
    phi += __shfl_xor(phi, 2);
    phi += __shfl_xor(phi, 4);

    float wi = 0.5f / phi * tanhf(0.5f * phi);
    float A  = (bv[i] - 0.5f) - phi * wi;     // all lanes (broadcast bv load)

    *(float4*)(LpBuf + (size_t)i * RDIM + sub * 4) = Lp;

    if (sub == 0) scal[i] = make_float2(A, wi);   // fp32, overflow path only

    if (sub < 3) {
        int row  = (sub == 0) ? e0 : (sub == 1) ? e1 : e2;
        int rid  = sub * NROW + row;
        int slot = atomicAdd(&cnt[rid], 1);
        if (slot < CAPB) {
            int packed = (int)((f2bf(A) << 16) | f2bf(wi));
            *(int2*)(bucket2 + (size_t)rid * 8 + slot * 2) = make_int2(i, packed);
        } else {
            int idx = i * 3 + sub;                       // idx+1 encoding
            nxt[idx] = atomicExch(&head[rid], idx + 1);
        }
    }
}

// ---------------------------------------------------------------------------
#define ACCS(SA, TA, RG, Aj, Wj, P)                                     \
{                                                                       \
    float cx = (P).x * (RG).x, cy = (P).y * (RG).y,                     \
          cz = (P).z * (RG).z, cw = (P).w * (RG).w;                     \
    (SA).x += (Wj) * cx * cx;  (SA).y += (Wj) * cy * cy;                \
    (SA).z += (Wj) * cz * cz;  (SA).w += (Wj) * cw * cw;                \
    (TA).x += ((Aj) + (Wj) * (P).x) * cx;                               \
    (TA).y += ((Aj) + (Wj) * (P).y) * cy;                               \
    (TA).z += ((Aj) + (Wj) * (P).z) * cz;                               \
    (TA).w += ((Aj) + (Wj) * (P).w) * cw;                               \
}

// 8 lanes/row. r7's flat burst structure; aw inline in bucket (no scal lines).
__global__ __launch_bounds__(256) void em_apply_v11(
    const float* __restrict__ U0, const float* __restrict__ U1,
    const float* __restrict__ U2,
    const float* __restrict__ S0, const float* __restrict__ S1,
    const float* __restrict__ S2,
    const float* __restrict__ T0, const float* __restrict__ T1,
    const float* __restrict__ T2,
    const int* __restrict__ cnt, const int* __restrict__ head,
    const int* __restrict__ nxt, const int* __restrict__ bucket2,
    const float2* __restrict__ scal, const float* __restrict__ LpBuf,
    float* __restrict__ out)
{
    int tid = blockIdx.x * blockDim.x + threadIdx.x;
    int rid = tid >> 3;          // [0, ROWS3)
    int sub = tid & 7;
    if (rid >= ROWS3) return;

    int d   = rid / NROW;        // uniform per block (NROW % 32 == 0)
    int row = rid - d * NROW;

    const float* Ud   = (d == 0) ? U0 : (d == 1) ? U1 : U2;
    const float* Ssrc = (d == 0) ? S0 : (d == 1) ? S1 : S2;
    const float* Tsrc = (d == 0) ? T0 : (d == 1) ? T1 : T2;

    size_t roff = (size_t)row * RDIM + sub * 4;

    // -------- level-1 burst: all independent, coalesced --------
    int    n    = cnt[rid];
    const int* brow = bucket2 + (size_t)rid * 8;
    int4   b01  = *(const int4*)(brow);       // e0,p0,e1,p1
    int4   b23  = *(const int4*)(brow + 4);   // e2,p2,e3,p3
    float4 s_in = *(const float4*)(Ssrc + roff);
    float4 t_in = *(const float4*)(Tsrc + roff);

    // -------- level-2 burst: indices straight from registers --------
    int i0 = (n > 0) ? b01.x : 0;
    int i1 = (n > 1) ? b01.z : 0;
    int i2 = (n > 2) ? b23.x : 0;
    int i3 = (n > 3) ? b23.z : 0;

    float4 p0 = *(const float4*)(LpBuf + (size_t)i0 * RDIM + sub * 4);
    float4 p1 = *(const float4*)(LpBuf + (size_t)i1 * RDIM + sub * 4);
    float4 p2 = *(const float4*)(LpBuf + (size_t)i2 * RDIM + sub * 4);
    float4 p3 = *(const float4*)(LpBuf + (size_t)i3 * RDIM + sub * 4);

    // unpack inline aw; mask unused slots (slot0 masked by final select)
    float A0 = bf2f(((unsigned)b01.y) >> 16), W0 = bf2f(((unsigned)b01.y) & 0xffffu);
    float A1 = bf2f(((unsigned)b01.w) >> 16), W1 = bf2f(((unsigned)b01.w) & 0xffffu);
    float A2 = bf2f(((unsigned)b23.y) >> 16), W2 = bf2f(((unsigned)b23.y) & 0xffffu);
    float A3 = bf2f(((unsigned)b23.w) >> 16), W3 = bf2f(((unsigned)b23.w) & 0xffffu);
    if (n <= 1) { A1 = 0.f; W1 = 0.f; }
    if (n <= 2) { A2 = 0.f; W2 = 0.f; }
    if (n <= 3) { A3 = 0.f; W3 = 0.f; }

    // Ud + rcp guarded (saves ~37 MB of lines on untouched rows)
    float4 rg = make_float4(0.f, 0.f, 0.f, 0.f);
    if (n > 0) {
        float4 gd = *(const float4*)(Ud + roff);
        rg.x = __builtin_amdgcn_rcpf(gd.x);   // U in [0.05,1] — safe
        rg.y = __builtin_amdgcn_rcpf(gd.y);
        rg.z = __builtin_amdgcn_rcpf(gd.z);
        rg.w = __builtin_amdgcn_rcpf(gd.w);
    }

    float4 sa = make_float4(0.f, 0.f, 0.f, 0.f);
    float4 ta = make_float4(0.f, 0.f, 0.f, 0.f);

    ACCS(sa, ta, rg, A0, W0, p0)
    ACCS(sa, ta, rg, A1, W1, p1)
    ACCS(sa, ta, rg, A2, W2, p2)
    ACCS(sa, ta, rg, A3, W3, p3)

    if (n > CAPB) {   // cold: ~3.5e-4 of rows; fp32 scal chain
        int t = head[rid];
        while (t != 0) {
            int idx = t - 1;
            int e   = idx / 3;
            float2 aw = scal[e];
            float4 P  = *(const float4*)(LpBuf + (size_t)e * RDIM + sub * 4);
            ACCS(sa, ta, rg, aw.x, aw.y, P)
            t = nxt[idx];
        }
    }

    bool touched = (n > 0);
    float4 oS, oT;
    oS.x = touched ? (1.0f - STEP) * s_in.x + STEP * sa.x : s_in.x;
    oS.y = touched ? (1.0f - STEP) * s_in.y + STEP * sa.y : s_in.y;
    oS.z = touched ? (1.0f - STEP) * s_in.z + STEP * sa.z : s_in.z;
    oS.w = touched ? (1.0f - STEP) * s_in.w + STEP * sa.w : s_in.w;
    oT.x = touched ? (1.0f - STEP) * t_in.x + STEP * ta.x : t_in.x;
    oT.y = touched ? (1.0f - STEP) * t_in.y + STEP * ta.y : t_in.y;
    oT.z = touched ? (1.0f - STEP) * t_in.z + STEP * ta.z : t_in.z;
    oT.w = touched ? (1.0f - STEP) * t_in.w + STEP * ta.w : t_in.w;

    size_t off = (size_t)rid * RDIM + sub * 4;
    *(float4*)(out + off) = oS;
    *(float4*)(out + (size_t)ROWS3 * RDIM + off) = oT;
}

// ===========================================================================
// FALLBACK (chain version) — used only if ws too small for buckets
// ===========================================================================
__global__ __launch_bounds__(256) void em_pre(
    const float* __restrict__ U0, const float* __restrict__ U1,
    const float* __restrict__ U2, const float* __restrict__ L,
    const float* __restrict__ bv, const int* __restrict__ be,
    int* __restrict__ head, int* __restrict__ nxt,
    float2* __restrict__ scal, float* __restrict__ LpBuf)
{
    int tid = blockIdx.x * blockDim.x + threadIdx.x;
    int i   = tid >> 3;
    int sub = tid & 7;
    if (i >= BATCH) return;

    int e0 = be[i * 3 + 0];
    int e1 = be[i * 3 + 1];
    int e2 = be[i * 3 + 2];

    float4 g0 = *(const float4*)(U0 + (size_t)e0 * RDIM + sub * 4);
    float4 g1 = *(const float4*)(U1 + (size_t)e1 * RDIM + sub * 4);
    float4 g2 = *(const float4*)(U2 + (size_t)e2 * RDIM + sub * 4);
    float4 Lv = *(const float4*)(L + sub * 4);

    float4 Lp;
    Lp.x = Lv.x * g0.x * g1.x * g2.x;
    Lp.y = Lv.y * g0.y * g1.y * g2.y;
    Lp.z = Lv.z * g0.z * g1.z * g2.z;
    Lp.w = Lv.w * g0.w * g1.w * g2.w;

    float phi = (Lp.x + Lp.y) + (Lp.z + Lp.w);
    phi += __shfl_xor(phi, 1);
    phi += __shfl_xor(phi, 2);
    phi += __shfl_xor(phi, 4);

    float wi = 0.5f / phi * tanhf(0.5f * phi);

    *(float4*)(LpBuf + (size_t)i * RDIM + sub * 4) = Lp;

    if (sub == 0) {
        float A = (bv[i] - 0.5f) - phi * wi;
        scal[i] = make_float2(A, wi);
    }
    if (sub < 3) {
        int row = (sub == 0) ? e0 : (sub == 1) ? e1 : e2;
        int idx = i * 3 + sub;
        nxt[idx] = atomicExch(&head[sub * NROW + row], idx + 1);
    }
}

__global__ __launch_bounds__(256) void em_apply_vec(
    const float* __restrict__ U0, const float* __restrict__ U1,
    const float* __restrict__ U2,
    const float* __restrict__ S0, const float* __restrict__ S1,
    const float* __restrict__ S2,
    const float* __restrict__ T0, const float* __restrict__ T1,
    const float* __restrict__ T2,
    const int* __restrict__ head, const int* __restrict__ nxt,
    const float2* __restrict__ scal, const float* __restrict__ LpBuf,
    float* __restrict__ out)
{
    int tid = blockIdx.x * blockDim.x + threadIdx.x;
    int rid = tid >> 3;
    int sub = tid & 7;
    if (rid >= ROWS3) return;

    int d   = rid / NROW;
    int row = rid - d * NROW;

    const float* Ud   = (d == 0) ? U0 : (d == 1) ? U1 : U2;
    const float* Ssrc = (d == 0) ? S0 : (d == 1) ? S1 : S2;
    const float* Tsrc = (d == 0) ? T0 : (d == 1) ? T1 : T2;

    size_t roff = (size_t)row * RDIM + sub * 4;
    float4 s_in = *(const float4*)(Ssrc + roff);
    float4 t_in = *(const float4*)(Tsrc + roff);

    int    t  = head[rid];
    float4 oS = s_in;
    float4 oT = t_in;

    if (t != 0) {
        float4 gd = *(const float4*)(Ud + roff);
        float4 rg;
        rg.x = __builtin_amdgcn_rcpf(gd.x);
        rg.y = __builtin_amdgcn_rcpf(gd.y);
        rg.z = __builtin_amdgcn_rcpf(gd.z);
        rg.w = __builtin_amdgcn_rcpf(gd.w);

        float4 sa = make_float4(0.f, 0.f, 0.f, 0.f);
        float4 ta = make_float4(0.f, 0.f, 0.f, 0.f);
        while (t != 0) {
            int idx = t - 1;
            int e = idx / 3;
            float2 aw = scal[e];
            float4 Lp = *(const float4*)(LpBuf + (size_t)e * RDIM + sub * 4);
            ACCS(sa, ta, rg, aw.x, aw.y, Lp)
            t = nxt[idx];
        }
        oS.x = (1.0f - STEP) * s_in.x + STEP * sa.x;
        oS.y = (1.0f - STEP) * s_in.y + STEP * sa.y;
        oS.z = (1.0f - STEP) * s_in.z + STEP * sa.z;
        oS.w = (1.0f - STEP) * s_in.w + STEP * sa.w;
        oT.x = (1.0f - STEP) * t_in.x + STEP * ta.x;
        oT.y = (1.0f - STEP) * t_in.y + STEP * ta.y;
        oT.z = (1.0f - STEP) * t_in.z + STEP * ta.z;
        oT.w = (1.0f - STEP) * t_in.w + STEP * ta.w;
    }

    size_t offS = (size_t)rid * RDIM + sub * 4;
    *(float4*)(out + offS) = oS;
    *(float4*)(out + (size_t)ROWS3 * RDIM + offS) = oT;
}

// ===========================================================================
extern "C" void kernel_launch(void* const* d_in, const int* in_sizes, int n_in,
                              void* d_out, int out_size, void* d_ws, size_t ws_size,
                              hipStream_t stream)
{
    // setup_inputs() insertion order: U0,S0,T0, U1,S1,T1, U2,S2,T2, L, bv, be
    const float* U0 = (const float*)d_in[0];
    const float* S0 = (const float*)d_in[1];
    const float* T0 = (const float*)d_in[2];
    const float* U1 = (const float*)d_in[3];
    const float* S1 = (const float*)d_in[4];
    const float* T1 = (const float*)d_in[5];
    const float* U2 = (const float*)d_in[6];
    const float* S2 = (const float*)d_in[7];
    const float* T2 = (const float*)d_in[8];
    const float* L  = (const float*)d_in[9];
    const float* bv = (const float*)d_in[10];
    const int*   be = (const int*)d_in[11];

    float* out = (float*)d_out;

    const size_t rows3 = (size_t)ROWS3;
    const size_t nxt_n = (size_t)3 * BATCH;
    const size_t bk2_n = rows3 * 8;          // ints (32B/row)

    const size_t ws_fast = (2 * rows3 + nxt_n + bk2_n) * sizeof(int)
                         + (size_t)BATCH * sizeof(float2)
                         + (size_t)BATCH * RDIM * sizeof(float);   // ~43.4 MB
    const size_t ws_mid  = (rows3 + nxt_n) * sizeof(int)
                         + (size_t)BATCH * sizeof(float2)
                         + (size_t)BATCH * RDIM * sizeof(float);   // ~21.8 MB

    if (ws_size >= ws_fast) {
        // ---- fast path: inline-aw buckets + flat burst apply ----
        int*    cnt     = (int*)d_ws;
        int*    head_   = cnt + rows3;
        int*    nxt     = head_ + rows3;
        int*    bucket2 = nxt + nxt_n;
        float2* scal    = (float2*)(bucket2 + bk2_n);
        float*  LpBuf   = (float*)(scal + BATCH);

        // cnt=0 and head=0 (idx+1 encoding) in ONE memset
        hipMemsetAsync(cnt, 0, 2 * rows3 * sizeof(int), stream);

        int pblocks = (BATCH * 8 + 255) / 256;    // 4096
        em_pre_v11<<<pblocks, 256, 0, stream>>>(U0, U1, U2, L, bv, be,
                                                cnt, head_, nxt, bucket2,
                                                scal, LpBuf);

        long athreads = (long)ROWS3 * 8;          // 4.8M
        int  ablocks  = (int)((athreads + 255) / 256);  // 18750
        em_apply_v11<<<ablocks, 256, 0, stream>>>(U0, U1, U2, S0, S1, S2,
                                                  T0, T1, T2, cnt, head_, nxt,
                                                  bucket2, scal, LpBuf, out);
    } else if (ws_size >= ws_mid) {
        // ---- fallback: linked-list version ----
        int*    head_ = (int*)d_ws;
        int*    nxt   = head_ + rows3;
        float2* scal  = (float2*)(nxt + nxt_n);
        float*  LpBuf = (float*)(scal + BATCH);

        hipMemsetAsync(head_, 0, rows3 * sizeof(int), stream);

        int pblocks = (BATCH * 8 + 255) / 256;
        em_pre<<<pblocks, 256, 0, stream>>>(U0, U1, U2, L, bv, be,
                                            head_, nxt, scal, LpBuf);

        long athreads = (long)ROWS3 * 8;
        int  ablocks  = (int)((athreads + 255) / 256);
        em_apply_vec<<<ablocks, 256, 0, stream>>>(U0, U1, U2, S0, S1, S2,
                                                  T0, T1, T2, head_, nxt,
                                                  scal, LpBuf, out);
    }
}

// Round 12
// 106.014 us; speedup vs baseline: 1.1605x; 1.0092x over previous
//
#include <hip/hip_runtime.h>

#define NROW 200000
#define RDIM 32
#define BATCH 131072
#define STEP 0.01f
#define CAPB 4                      // slots/row; P(n>4) ~ 3.5e-4/row
#define ROWS3 (3 * NROW)            // 600000

// ===========================================================================
// V12 ws layout (~331.4 MB), in order:
//   cnt   int[ROWS3]        \ one contiguous memset(0)
//   head  int[ROWS3]        /  (idx+1 encoding; 0 = empty; overflow only)
//   nxt   int[3*BATCH]
//   scal  float2[BATCH]     (A, wi) fp32 — overflow cold path only
//   Lp    float[BATCH*32]   — overflow cold path only
//   fat   uint[ROWS3*CAPB*32]  128B/slot: per-lane uint4 {s01,s23,t01,t23} bf16x2
// V11 fallback layout (~43.4 MB) if ws too small.
// ===========================================================================

__device__ __forceinline__ unsigned f2bf(float x) {
    unsigned u = __float_as_uint(x);
    return (u + 0x8000u) >> 16;
}
__device__ __forceinline__ float bf2f(unsigned h) { return __uint_as_float(h << 16); }
__device__ __forceinline__ float bfhi(unsigned u) { return __uint_as_float(u & 0xffff0000u); }
__device__ __forceinline__ float bflo(unsigned u) { return __uint_as_float(u << 16); }
__device__ __forceinline__ unsigned pk2(float hi, float lo) {
    return (f2bf(hi) << 16) | f2bf(lo);
}

#define ACCS(SA, TA, RG, Aj, Wj, P)                                     \
{                                                                       \
    float cx = (P).x * (RG).x, cy = (P).y * (RG).y,                     \
          cz = (P).z * (RG).z, cw = (P).w * (RG).w;                     \
    (SA).x += (Wj) * cx * cx;  (SA).y += (Wj) * cy * cy;                \
    (SA).z += (Wj) * cz * cz;  (SA).w += (Wj) * cw * cw;                \
    (TA).x += ((Aj) + (Wj) * (P).x) * cx;                               \
    (TA).y += ((Aj) + (Wj) * (P).y) * cy;                               \
    (TA).z += ((Aj) + (Wj) * (P).z) * cz;                               \
    (TA).w += ((Aj) + (Wj) * (P).w) * cw;                               \
}

// ===========================================================================
// V12 pre: computes FULL contribution vectors, scatters 128B payloads.
// ===========================================================================
__global__ __launch_bounds__(256) void em_pre_v12(
    const float* __restrict__ U0, const float* __restrict__ U1,
    const float* __restrict__ U2, const float* __restrict__ L,
    const float* __restrict__ bv, const int* __restrict__ be,
    int* __restrict__ cnt, int* __restrict__ head, int* __restrict__ nxt,
    float2* __restrict__ scal, float* __restrict__ LpBuf,
    unsigned* __restrict__ fat)
{
    int tid = blockIdx.x * blockDim.x + threadIdx.x;
    int i   = tid >> 3;          // batch element
    int sub = tid & 7;           // 4-float slot
    if (i >= BATCH) return;

    int e0 = be[i * 3 + 0];
    int e1 = be[i * 3 + 1];
    int e2 = be[i * 3 + 2];

    float4 g0 = *(const float4*)(U0 + (size_t)e0 * RDIM + sub * 4);
    float4 g1 = *(const float4*)(U1 + (size_t)e1 * RDIM + sub * 4);
    float4 g2 = *(const float4*)(U2 + (size_t)e2 * RDIM + sub * 4);
    float4 Lv = *(const float4*)(L + sub * 4);

    float4 Lp;
    Lp.x = Lv.x * g0.x * g1.x * g2.x;
    Lp.y = Lv.y * g0.y * g1.y * g2.y;
    Lp.z = Lv.z * g0.z * g1.z * g2.z;
    Lp.w = Lv.w * g0.w * g1.w * g2.w;

    float phi = (Lp.x + Lp.y) + (Lp.z + Lp.w);
    phi += __shfl_xor(phi, 1);
    phi += __shfl_xor(phi, 2);
    phi += __shfl_xor(phi, 4);

    float wi = 0.5f / phi * tanhf(0.5f * phi);
    float A  = (bv[i] - 0.5f) - phi * wi;

    *(float4*)(LpBuf + (size_t)i * RDIM + sub * 4) = Lp;   // overflow path
    if (sub == 0) scal[i] = make_float2(A, wi);            // overflow path

    // one slot per dim; lane d does the atomic, result broadcast to subgroup
    int slotv = 0;
    if (sub < 3) {
        int row = (sub == 0) ? e0 : (sub == 1) ? e1 : e2;
        int rid = sub * NROW + row;
        slotv = atomicAdd(&cnt[rid], 1);
        if (slotv >= CAPB) {
            int idx = i * 3 + sub;                        // idx+1 encoding
            nxt[idx] = atomicExch(&head[rid], idx + 1);
        }
    }
    int s0 = __shfl(slotv, 0, 8);
    int s1 = __shfl(slotv, 1, 8);
    int s2 = __shfl(slotv, 2, 8);

    // t-coefficient vector (A + wi*Lp), shared across dims
    float4 tc;
    tc.x = A + wi * Lp.x;  tc.y = A + wi * Lp.y;
    tc.z = A + wi * Lp.z;  tc.w = A + wi * Lp.w;

    #define EMIT(SLOT, RID, CA, CB)                                         \
    if ((SLOT) < CAPB) {                                                    \
        float4 c;                                                           \
        c.x = Lv.x * (CA).x * (CB).x;  c.y = Lv.y * (CA).y * (CB).y;        \
        c.z = Lv.z * (CA).z * (CB).z;  c.w = Lv.w * (CA).w * (CB).w;        \
        uint4 q;                                                            \
        q.x = pk2(wi * c.x * c.x, wi * c.y * c.y);                          \
        q.y = pk2(wi * c.z * c.z, wi * c.w * c.w);                          \
        q.z = pk2(tc.x * c.x, tc.y * c.y);                                  \
        q.w = pk2(tc.z * c.z, tc.w * c.w);                                  \
        *(uint4*)(fat + ((size_t)(RID) * CAPB + (SLOT)) * 32 + sub * 4) = q;\
    }

    EMIT(s0, 0 * NROW + e0, g1, g2)
    EMIT(s1, 1 * NROW + e1, g0, g2)
    EMIT(s2, 2 * NROW + e2, g0, g1)
    #undef EMIT
}

// ===========================================================================
// V12 apply: pure streaming — no gathers, no Ud, no rcp in the hot path.
// ===========================================================================
__global__ __launch_bounds__(256) void em_apply_v12(
    const float* __restrict__ U0, const float* __restrict__ U1,
    const float* __restrict__ U2,
    const float* __restrict__ S0, const float* __restrict__ S1,
    const float* __restrict__ S2,
    const float* __restrict__ T0, const float* __restrict__ T1,
    const float* __restrict__ T2,
    const int* __restrict__ cnt, const int* __restrict__ head,
    const int* __restrict__ nxt, const unsigned* __restrict__ fat,
    const float2* __restrict__ scal, const float* __restrict__ LpBuf,
    float* __restrict__ out)
{
    int tid = blockIdx.x * blockDim.x + threadIdx.x;
    int rid = tid >> 3;
    int sub = tid & 7;
    if (rid >= ROWS3) return;

    int d   = rid / NROW;        // uniform per block (NROW % 32 == 0)
    int row = rid - d * NROW;

    const float* Ssrc = (d == 0) ? S0 : (d == 1) ? S1 : S2;
    const float* Tsrc = (d == 0) ? T0 : (d == 1) ? T1 : T2;

    size_t roff = (size_t)row * RDIM + sub * 4;

    int    n    = cnt[rid];
    float4 s_in = *(const float4*)(Ssrc + roff);
    float4 t_in = *(const float4*)(Tsrc + roff);

    const unsigned* fb = fat + (size_t)rid * CAPB * 32 + sub * 4;
    uint4 q0 = make_uint4(0, 0, 0, 0);
    uint4 q1 = q0, q2 = q0, q3 = q0;
    if (n > 0) q0 = *(const uint4*)(fb);
    if (n > 1) q1 = *(const uint4*)(fb + 32);
    if (n > 2) q2 = *(const uint4*)(fb + 64);
    if (n > 3) q3 = *(const uint4*)(fb + 96);

    float4 sa = make_float4(0.f, 0.f, 0.f, 0.f);
    float4 ta = make_float4(0.f, 0.f, 0.f, 0.f);

    #define UACC(Q)                                         \
    {                                                       \
        sa.x += bfhi((Q).x);  sa.y += bflo((Q).x);          \
        sa.z += bfhi((Q).y);  sa.w += bflo((Q).y);          \
        ta.x += bfhi((Q).z);  ta.y += bflo((Q).z);          \
        ta.z += bfhi((Q).w);  ta.w += bflo((Q).w);          \
    }
    UACC(q0) UACC(q1) UACC(q2) UACC(q3)
    #undef UACC

    if (n > CAPB) {   // cold: ~3.5e-4 of rows; recompute via scal/LpBuf chain
        const float* Ud = (d == 0) ? U0 : (d == 1) ? U1 : U2;
        float4 gd = *(const float4*)(Ud + roff);
        float4 rg;
        rg.x = __builtin_amdgcn_rcpf(gd.x);
        rg.y = __builtin_amdgcn_rcpf(gd.y);
        rg.z = __builtin_amdgcn_rcpf(gd.z);
        rg.w = __builtin_amdgcn_rcpf(gd.w);
        int t = head[rid];
        while (t != 0) {
            int idx = t - 1;
            int e   = idx / 3;
            float2 aw = scal[e];
            float4 P  = *(const float4*)(LpBuf + (size_t)e * RDIM + sub * 4);
            ACCS(sa, ta, rg, aw.x, aw.y, P)
            t = nxt[idx];
        }
    }

    bool touched = (n > 0);
    float4 oS, oT;
    oS.x = touched ? (1.0f - STEP) * s_in.x + STEP * sa.x : s_in.x;
    oS.y = touched ? (1.0f - STEP) * s_in.y + STEP * sa.y : s_in.y;
    oS.z = touched ? (1.0f - STEP) * s_in.z + STEP * sa.z : s_in.z;
    oS.w = touched ? (1.0f - STEP) * s_in.w + STEP * sa.w : s_in.w;
    oT.x = touched ? (1.0f - STEP) * t_in.x + STEP * ta.x : t_in.x;
    oT.y = touched ? (1.0f - STEP) * t_in.y + STEP * ta.y : t_in.y;
    oT.z = touched ? (1.0f - STEP) * t_in.z + STEP * ta.z : t_in.z;
    oT.w = touched ? (1.0f - STEP) * t_in.w + STEP * ta.w : t_in.w;

    size_t off = (size_t)rid * RDIM + sub * 4;
    *(float4*)(out + off) = oS;
    *(float4*)(out + (size_t)ROWS3 * RDIM + off) = oT;
}

// ===========================================================================
// V11 FALLBACK (proven 107 µs path) — used if ws too small for v12
// ===========================================================================
__global__ __launch_bounds__(256) void em_pre_v11(
    const float* __restrict__ U0, const float* __restrict__ U1,
    const float* __restrict__ U2, const float* __restrict__ L,
    const float* __restrict__ bv, const int* __restrict__ be,
    int* __restrict__ cnt, int* __restrict__ head, int* __restrict__ nxt,
    int* __restrict__ bucket2, float2* __restrict__ scal, float* __restrict__ LpBuf)
{
    int tid = blockIdx.x * blockDim.x + threadIdx.x;
    int i   = tid >> 3;
    int sub = tid & 7;
    if (i >= BATCH) return;

    int e0 = be[i * 3 + 0];
    int e1 = be[i * 3 + 1];
    int e2 = be[i * 3 + 2];

    float4 g0 = *(const float4*)(U0 + (size_t)e0 * RDIM + sub * 4);
    float4 g1 = *(const float4*)(U1 + (size_t)e1 * RDIM + sub * 4);
    float4 g2 = *(const float4*)(U2 + (size_t)e2 * RDIM + sub * 4);
    float4 Lv = *(const float4*)(L + sub * 4);

    float4 Lp;
    Lp.x = Lv.x * g0.x * g1.x * g2.x;
    Lp.y = Lv.y * g0.y * g1.y * g2.y;
    Lp.z = Lv.z * g0.z * g1.z * g2.z;
    Lp.w = Lv.w * g0.w * g1.w * g2.w;

    float phi = (Lp.x + Lp.y) + (Lp.z + Lp.w);
    phi += __shfl_xor(phi, 1);
    phi += __shfl_xor(phi, 2);
    phi += __shfl_xor(phi, 4);

    float wi = 0.5f / phi * tanhf(0.5f * phi);
    float A  = (bv[i] - 0.5f) - phi * wi;

    *(float4*)(LpBuf + (size_t)i * RDIM + sub * 4) = Lp;

    if (sub == 0) scal[i] = make_float2(A, wi);

    if (sub < 3) {
        int row  = (sub == 0) ? e0 : (sub == 1) ? e1 : e2;
        int rid  = sub * NROW + row;
        int slot = atomicAdd(&cnt[rid], 1);
        if (slot < CAPB) {
            int packed = (int)((f2bf(A) << 16) | f2bf(wi));
            *(int2*)(bucket2 + (size_t)rid * 8 + slot * 2) = make_int2(i, packed);
        } else {
            int idx = i * 3 + sub;
            nxt[idx] = atomicExch(&head[rid], idx + 1);
        }
    }
}

__global__ __launch_bounds__(256) void em_apply_v11(
    const float* __restrict__ U0, const float* __restrict__ U1,
    const float* __restrict__ U2,
    const float* __restrict__ S0, const float* __restrict__ S1,
    const float* __restrict__ S2,
    const float* __restrict__ T0, const float* __restrict__ T1,
    const float* __restrict__ T2,
    const int* __restrict__ cnt, const int* __restrict__ head,
    const int* __restrict__ nxt, const int* __restrict__ bucket2,
    const float2* __restrict__ scal, const float* __restrict__ LpBuf,
    float* __restrict__ out)
{
    int tid = blockIdx.x * blockDim.x + threadIdx.x;
    int rid = tid >> 3;
    int sub = tid & 7;
    if (rid >= ROWS3) return;

    int d   = rid / NROW;
    int row = rid - d * NROW;

    const float* Ud   = (d == 0) ? U0 : (d == 1) ? U1 : U2;
    const float* Ssrc = (d == 0) ? S0 : (d == 1) ? S1 : S2;
    const float* Tsrc = (d == 0) ? T0 : (d == 1) ? T1 : T2;

    size_t roff = (size_t)row * RDIM + sub * 4;

    int    n    = cnt[rid];
    const int* brow = bucket2 + (size_t)rid * 8;
    int4   b01  = *(const int4*)(brow);
    int4   b23  = *(const int4*)(brow + 4);
    float4 s_in = *(const float4*)(Ssrc + roff);
    float4 t_in = *(const float4*)(Tsrc + roff);

    int i0 = (n > 0) ? b01.x : 0;
    int i1 = (n > 1) ? b01.z : 0;
    int i2 = (n > 2) ? b23.x : 0;
    int i3 = (n > 3) ? b23.z : 0;

    float4 p0 = *(const float4*)(LpBuf + (size_t)i0 * RDIM + sub * 4);
    float4 p1 = *(const float4*)(LpBuf + (size_t)i1 * RDIM + sub * 4);
    float4 p2 = *(const float4*)(LpBuf + (size_t)i2 * RDIM + sub * 4);
    float4 p3 = *(const float4*)(LpBuf + (size_t)i3 * RDIM + sub * 4);

    float A0 = bf2f(((unsigned)b01.y) >> 16), W0 = bf2f(((unsigned)b01.y) & 0xffffu);
    float A1 = bf2f(((unsigned)b01.w) >> 16), W1 = bf2f(((unsigned)b01.w) & 0xffffu);
    float A2 = bf2f(((unsigned)b23.y) >> 16), W2 = bf2f(((unsigned)b23.y) & 0xffffu);
    float A3 = bf2f(((unsigned)b23.w) >> 16), W3 = bf2f(((unsigned)b23.w) & 0xffffu);
    if (n <= 1) { A1 = 0.f; W1 = 0.f; }
    if (n <= 2) { A2 = 0.f; W2 = 0.f; }
    if (n <= 3) { A3 = 0.f; W3 = 0.f; }

    float4 rg = make_float4(0.f, 0.f, 0.f, 0.f);
    if (n > 0) {
        float4 gd = *(const float4*)(Ud + roff);
        rg.x = __builtin_amdgcn_rcpf(gd.x);
        rg.y = __builtin_amdgcn_rcpf(gd.y);
        rg.z = __builtin_amdgcn_rcpf(gd.z);
        rg.w = __builtin_amdgcn_rcpf(gd.w);
    }

    float4 sa = make_float4(0.f, 0.f, 0.f, 0.f);
    float4 ta = make_float4(0.f, 0.f, 0.f, 0.f);

    ACCS(sa, ta, rg, A0, W0, p0)
    ACCS(sa, ta, rg, A1, W1, p1)
    ACCS(sa, ta, rg, A2, W2, p2)
    ACCS(sa, ta, rg, A3, W3, p3)

    if (n > CAPB) {
        int t = head[rid];
        while (t != 0) {
            int idx = t - 1;
            int e   = idx / 3;
            float2 aw = scal[e];
            float4 P  = *(const float4*)(LpBuf + (size_t)e * RDIM + sub * 4);
            ACCS(sa, ta, rg, aw.x, aw.y, P)
            t = nxt[idx];
        }
    }

    bool touched = (n > 0);
    float4 oS, oT;
    oS.x = touched ? (1.0f - STEP) * s_in.x + STEP * sa.x : s_in.x;
    oS.y = touched ? (1.0f - STEP) * s_in.y + STEP * sa.y : s_in.y;
    oS.z = touched ? (1.0f - STEP) * s_in.z + STEP * sa.z : s_in.z;
    oS.w = touched ? (1.0f - STEP) * s_in.w + STEP * sa.w : s_in.w;
    oT.x = touched ? (1.0f - STEP) * t_in.x + STEP * ta.x : t_in.x;
    oT.y = touched ? (1.0f - STEP) * t_in.y + STEP * ta.y : t_in.y;
    oT.z = touched ? (1.0f - STEP) * t_in.z + STEP * ta.z : t_in.z;
    oT.w = touched ? (1.0f - STEP) * t_in.w + STEP * ta.w : t_in.w;

    size_t off = (size_t)rid * RDIM + sub * 4;
    *(float4*)(out + off) = oS;
    *(float4*)(out + (size_t)ROWS3 * RDIM + off) = oT;
}

// ===========================================================================
extern "C" void kernel_launch(void* const* d_in, const int* in_sizes, int n_in,
                              void* d_out, int out_size, void* d_ws, size_t ws_size,
                              hipStream_t stream)
{
    // setup_inputs() insertion order: U0,S0,T0, U1,S1,T1, U2,S2,T2, L, bv, be
    const float* U0 = (const float*)d_in[0];
    const float* S0 = (const float*)d_in[1];
    const float* T0 = (const float*)d_in[2];
    const float* U1 = (const float*)d_in[3];
    const float* S1 = (const float*)d_in[4];
    const float* T1 = (const float*)d_in[5];
    const float* U2 = (const float*)d_in[6];
    const float* S2 = (const float*)d_in[7];
    const float* T2 = (const float*)d_in[8];
    const float* L  = (const float*)d_in[9];
    const float* bv = (const float*)d_in[10];
    const int*   be = (const int*)d_in[11];

    float* out = (float*)d_out;

    const size_t rows3 = (size_t)ROWS3;
    const size_t nxt_n = (size_t)3 * BATCH;

    // v12 layout
    const size_t ws_v12 = (2 * rows3 + nxt_n) * sizeof(int)
                        + (size_t)BATCH * sizeof(float2)
                        + (size_t)BATCH * RDIM * sizeof(float)
                        + rows3 * CAPB * 32 * sizeof(unsigned);   // ~331.4 MB
    // v11 layout
    const size_t bk2_n  = rows3 * 8;
    const size_t ws_v11 = (2 * rows3 + nxt_n + bk2_n) * sizeof(int)
                        + (size_t)BATCH * sizeof(float2)
                        + (size_t)BATCH * RDIM * sizeof(float);   // ~43.4 MB

    int pblocks = (BATCH * 8 + 255) / 256;            // 4096
    long athreads = (long)ROWS3 * 8;                  // 4.8M
    int  ablocks  = (int)((athreads + 255) / 256);    // 18750

    if (ws_size >= ws_v12) {
        // ---- v12: full-contribution fat slots; streaming apply ----
        int*      cnt   = (int*)d_ws;
        int*      head_ = cnt + rows3;
        int*      nxt   = head_ + rows3;
        float2*   scal  = (float2*)(nxt + nxt_n);
        float*    LpBuf = (float*)(scal + BATCH);
        unsigned* fat   = (unsigned*)(LpBuf + (size_t)BATCH * RDIM);

        hipMemsetAsync(cnt, 0, 2 * rows3 * sizeof(int), stream);

        em_pre_v12<<<pblocks, 256, 0, stream>>>(U0, U1, U2, L, bv, be,
                                                cnt, head_, nxt, scal, LpBuf, fat);
        em_apply_v12<<<ablocks, 256, 0, stream>>>(U0, U1, U2, S0, S1, S2,
                                                  T0, T1, T2, cnt, head_, nxt,
                                                  fat, scal, LpBuf, out);
    } else if (ws_size >= ws_v11) {
        // ---- v11 fallback (proven) ----
        int*    cnt     = (int*)d_ws;
        int*    head_   = cnt + rows3;
        int*    nxt     = head_ + rows3;
        int*    bucket2 = nxt + nxt_n;
        float2* scal    = (float2*)(bucket2 + bk2_n);
        float*  LpBuf   = (float*)(scal + BATCH);

        hipMemsetAsync(cnt, 0, 2 * rows3 * sizeof(int), stream);

        em_pre_v11<<<pblocks, 256, 0, stream>>>(U0, U1, U2, L, bv, be,
                                                cnt, head_, nxt, bucket2,
                                                scal, LpBuf);
        em_apply_v11<<<ablocks, 256, 0, stream>>>(U0, U1, U2, S0, S1, S2,
                                                  T0, T1, T2, cnt, head_, nxt,
                                                  bucket2, scal, LpBuf, out);
    }
}